// Round 5
// baseline (162.572 us; speedup 1.0000x reference)
//
#include <hip/hip_runtime.h>

#define NBINS   20
#define NSETS   32          // replicated global accumulator slots (power of 2)
#define BLOCKS  2048
#define TPB     256
#define PACK    256.0f      // A = 256*cnt + sse ; per-thread cnt<=32, sse<32 -> exact decode

// Per-tile compute: 4 elements -> packed (cnt,sse) routed into 20 register bins.
// All acc indexing is compile-time (full unroll) -> stays in VGPRs (no scratch).
__device__ __forceinline__ void body(const float4 p, const float4 t, float (&acc)[NBINS])
{
    float d0 = p.x - t.x; float a0 = fmaf(d0, d0, PACK);
    float d1 = p.y - t.y; float a1 = fmaf(d1, d1, PACK);
    float d2 = p.z - t.z; float a2 = fmaf(d2, d2, PACK);
    float d3 = p.w - t.w; float a3 = fmaf(d3, d3, PACK);
    int b0 = min(max((int)(t.x * 20.0f), 0), NBINS - 1);
    int b1 = min(max((int)(t.y * 20.0f), 0), NBINS - 1);
    int b2 = min(max((int)(t.z * 20.0f), 0), NBINS - 1);
    int b3 = min(max((int)(t.w * 20.0f), 0), NBINS - 1);
    #pragma unroll
    for (int bb = 0; bb < NBINS; ++bb) {
        float add = ((bb == b0) ? a0 : 0.0f) + ((bb == b1) ? a1 : 0.0f)
                  + ((bb == b2) ? a2 : 0.0f) + ((bb == b3) ? a3 : 0.0f);
        acc[bb] += add;
    }
}

// ---------------- Pass 1: per-bin packed (count,sse) histogram ----------------
// r2 win: register-resident bin accumulators (no LDS on the element path).
// r4 fix: BRANCH-FREE counted main loop with UNCONDITIONAL loads. The r3
// pipeline failed because conditional loads (`if (mk) pk=...`) split basic
// blocks and forced vmcnt(0) drains each iteration (VALU and memory ran
// serialized: 48% VALUBusy). A single-basic-block loop lets the compiler keep
// 4 loads in flight with counted s_waitcnt vmcnt(4).
__global__ __launch_bounds__(TPB, 8)
void dwmse_pass1(const float* __restrict__ pred, const float* __restrict__ targ,
                 float* __restrict__ ws, int n, int setMask)
{
    __shared__ float h[NBINS * TPB];     // 20 KB -> 8 blocks/CU
    const int tid = threadIdx.x;

    float acc[NBINS];
    #pragma unroll
    for (int b = 0; b < NBINS; ++b) acc[b] = 0.0f;

    const int n4 = n >> 2;
    const float4* p4 = reinterpret_cast<const float4*>(pred);
    const float4* t4 = reinterpret_cast<const float4*>(targ);
    const int idx0    = blockIdx.x * TPB + tid;
    const int gstride = gridDim.x * TPB;

    const int iters = n4 / gstride;          // full tiles for every thread (8 @ N=2^24)
    const int rem   = n4 - iters * gstride;  // threads idx0 < rem do one extra tile

    if (iters >= 2) {
        const float4* pp = p4 + idx0;
        const float4* tt = t4 + idx0;
        float4 pa = pp[0];       float4 ta = tt[0];
        float4 pb = pp[gstride]; float4 tb = tt[gstride];
        // steady state: single basic block, unconditional 2-ahead loads
        for (int it = 0; it < iters - 2; ++it) {
            float4 pc = pp[2 * gstride];
            float4 tc = tt[2 * gstride];
            pp += gstride; tt += gstride;
            body(pa, ta, acc);
            pa = pb; ta = tb;
            pb = pc; tb = tc;
        }
        body(pa, ta, acc);
        body(pb, tb, acc);
    } else if (iters == 1) {
        body(p4[idx0], t4[idx0], acc);
    }
    if (idx0 < rem) {
        body(p4[iters * gstride + idx0], t4[iters * gstride + idx0], acc);
    }
    // scalar tail (empty for N = 2^24)
    for (int k = (n4 << 2) + idx0; k < n; k += gstride) {
        float t = targ[k];
        float d = pred[k] - t; float a = fmaf(d, d, PACK);
        int b = min(max((int)(t * 20.0f), 0), NBINS - 1);
        #pragma unroll
        for (int bb = 0; bb < NBINS; ++bb) acc[bb] += (bb == b) ? a : 0.0f;
    }

    // ---- decode per thread (exact: cnt<=32, sse<32), stage sse in LDS ----
    #pragma unroll
    for (int b = 0; b < NBINS; ++b) {
        float A = acc[b];
        float c = floorf(A * (1.0f / 256.0f));
        float s = A - 256.0f * c;
        h[b * TPB + tid] = s;            // phase A payload
        acc[b] = c;                      // keep counts for phase B
    }
    __syncthreads();

    // ---- phase A: 160 readers, each sums 32 consecutive (staggered) slots ----
    const int rbin = tid >> 3;           // bin for readers (tid < 160)
    const int rchk = tid & 7;            // chunk within bin
    float pA = 0.0f;
    if (tid < NBINS * 8) {
        const int base = rbin * TPB + rchk * 32;
        #pragma unroll
        for (int k = 0; k < 32; ++k)
            pA += h[base + ((k + tid) & 31)];   // stagger -> conflict-free
    }
    pA += __shfl_down(pA, 4);            // combine 8 chunks (aligned groups)
    pA += __shfl_down(pA, 2);
    pA += __shfl_down(pA, 1);
    const float blk_sse = pA;            // valid at rchk==0

    __syncthreads();                     // phase A reads done -> reuse h
    #pragma unroll
    for (int b = 0; b < NBINS; ++b) h[b * TPB + tid] = acc[b];
    __syncthreads();

    float pB = 0.0f;
    if (tid < NBINS * 8) {
        const int base = rbin * TPB + rchk * 32;
        #pragma unroll
        for (int k = 0; k < 32; ++k)
            pB += h[base + ((k + tid) & 31)];
    }
    pB += __shfl_down(pB, 4);
    pB += __shfl_down(pB, 2);
    pB += __shfl_down(pB, 1);

    if (tid < NBINS * 8 && rchk == 0) {
        const int set = (int)(blockIdx.x) & setMask;
        unsafeAtomicAdd(&ws[set * 2 * NBINS + rbin], blk_sse);
        unsafeAtomicAdd(&ws[set * 2 * NBINS + NBINS + rbin], pB);
    }
}

// ---------------- Pass 2: weights + final scalar ----------------
__global__ void dwmse_pass2(const float* __restrict__ ws, float* __restrict__ out,
                            int nsets, float inv_n)
{
    const int t = threadIdx.x;   // 64 threads = 1 wave
    float col = 0.0f;
    if (t < 2 * NBINS) {
        for (int s = 0; s < nsets; ++s) col += ws[s * 2 * NBINS + t];
    }
    // lanes 0..19 hold sse_b; counts live in lanes 20..39
    float sse = col;
    float cnt = __shfl(col, t + 20);

    float w = 0.0f;
    if (t < NBINS) {
        float c = fmaxf(cnt, 1.0f);
        w = __powf(c, -0.9f);
    }
    float s = w;
    #pragma unroll
    for (int off = 32; off > 0; off >>= 1) s += __shfl_down(s, off);
    s = __shfl(s, 0);

    float wb = (s > 0.0f) ? (w * (20.0f / s)) : w;
    wb = fmaxf(wb, 1.0f);

    float contrib = (t < NBINS) ? (wb * sse) : 0.0f;
    #pragma unroll
    for (int off = 32; off > 0; off >>= 1) contrib += __shfl_down(contrib, off);

    if (t == 0) out[0] = contrib * inv_n;
}

extern "C" void kernel_launch(void* const* d_in, const int* in_sizes, int n_in,
                              void* d_out, int out_size, void* d_ws, size_t ws_size,
                              hipStream_t stream)
{
    const float* pred = (const float*)d_in[0];
    const float* targ = (const float*)d_in[1];
    float*       out  = (float*)d_out;
    float*       ws   = (float*)d_ws;
    const int n = in_sizes[0];

    int nsets = NSETS;
    while ((size_t)nsets * 2 * NBINS * sizeof(float) > ws_size && nsets > 1) nsets >>= 1;

    hipMemsetAsync(d_ws, 0, (size_t)nsets * 2 * NBINS * sizeof(float), stream);
    dwmse_pass1<<<BLOCKS, TPB, 0, stream>>>(pred, targ, ws, n, nsets - 1);
    dwmse_pass2<<<1, 64, 0, stream>>>(ws, out, nsets, 1.0f / (float)n);
}

// Round 6
// 157.978 us; speedup vs baseline: 1.0291x; 1.0291x over previous
//
#include <hip/hip_runtime.h>

#define NBINS   20
#define NSETS   32          // replicated global accumulator slots (power of 2)
#define BLOCKS  4096        // -> iters = 4 exactly at N = 2^24 (specialized path)
#define TPB     256
#define PACK    256.0f      // A = 256*cnt + sse ; per-thread cnt<=32, sse<32 -> exact decode

// Per-tile compute: 4 elements -> packed (cnt,sse) routed into 20 register bins.
// All acc indexing is compile-time (full unroll) -> stays in VGPRs (no scratch).
__device__ __forceinline__ void body(const float4 p, const float4 t, float (&acc)[NBINS])
{
    float d0 = p.x - t.x; float a0 = fmaf(d0, d0, PACK);
    float d1 = p.y - t.y; float a1 = fmaf(d1, d1, PACK);
    float d2 = p.z - t.z; float a2 = fmaf(d2, d2, PACK);
    float d3 = p.w - t.w; float a3 = fmaf(d3, d3, PACK);
    int b0 = min(max((int)(t.x * 20.0f), 0), NBINS - 1);
    int b1 = min(max((int)(t.y * 20.0f), 0), NBINS - 1);
    int b2 = min(max((int)(t.z * 20.0f), 0), NBINS - 1);
    int b3 = min(max((int)(t.w * 20.0f), 0), NBINS - 1);
    #pragma unroll
    for (int bb = 0; bb < NBINS; ++bb) {
        float add = ((bb == b0) ? a0 : 0.0f) + ((bb == b1) ? a1 : 0.0f)
                  + ((bb == b2) ? a2 : 0.0f) + ((bb == b3) ? a3 : 0.0f);
        acc[bb] += add;
    }
}

// ---------------- Pass 1: per-bin packed (count,sse) histogram ----------------
// r2 win: register-resident bin accumulators (no LDS on the element path).
// r6 fix: launch_bounds min-waves 8 -> 4. The (TPB,8) bound capped VGPRs at 64,
// which forced the allocator to reuse load-destination registers and wait
// early — every source-level pipeline (r3 depth-2, r5 branch-free) compiled
// into a serialized loop (constant 52 us / 49% VALUBusy). With a 128-VGPR cap
// and iters==4, ALL 8 tile loads issue up-front in one basic block (8 KB MLP
// per wave); body0 waits vmcnt(6), the rest drain under compute.
__global__ __launch_bounds__(TPB, 4)
void dwmse_pass1(const float* __restrict__ pred, const float* __restrict__ targ,
                 float* __restrict__ ws, int n, int setMask)
{
    __shared__ float h[NBINS * TPB];     // 20 KB -> LDS caps 8 blocks/CU
    const int tid = threadIdx.x;

    float acc[NBINS];
    #pragma unroll
    for (int b = 0; b < NBINS; ++b) acc[b] = 0.0f;

    const int n4 = n >> 2;
    const float4* p4 = reinterpret_cast<const float4*>(pred);
    const float4* t4 = reinterpret_cast<const float4*>(targ);
    const int idx0    = blockIdx.x * TPB + tid;
    const int gstride = gridDim.x * TPB;

    const int iters = n4 / gstride;          // full tiles for every thread (4 @ N=2^24)
    const int rem   = n4 - iters * gstride;  // threads idx0 < rem do one extra tile

    if (iters == 4 && rem == 0) {
        // -------- specialized hot path: load everything, then compute --------
        const float4* pp = p4 + idx0;
        const float4* tt = t4 + idx0;
        float4 t0 = tt[0];
        float4 p0 = pp[0];
        float4 t1 = tt[gstride];
        float4 p1 = pp[gstride];
        float4 t2 = tt[2 * gstride];
        float4 p2 = pp[2 * gstride];
        float4 t3 = tt[3 * gstride];
        float4 p3 = pp[3 * gstride];
        body(p0, t0, acc);
        body(p1, t1, acc);
        body(p2, t2, acc);
        body(p3, t3, acc);
    } else {
        // -------- generic fallback (any n): branch-free counted pipeline -----
        if (iters >= 2) {
            const float4* pp = p4 + idx0;
            const float4* tt = t4 + idx0;
            float4 pa = pp[0];       float4 ta = tt[0];
            float4 pb = pp[gstride]; float4 tb = tt[gstride];
            for (int it = 0; it < iters - 2; ++it) {
                float4 pc = pp[2 * gstride];
                float4 tc = tt[2 * gstride];
                pp += gstride; tt += gstride;
                body(pa, ta, acc);
                pa = pb; ta = tb;
                pb = pc; tb = tc;
            }
            body(pa, ta, acc);
            body(pb, tb, acc);
        } else if (iters == 1) {
            body(p4[idx0], t4[idx0], acc);
        }
        if (idx0 < rem) {
            body(p4[iters * gstride + idx0], t4[iters * gstride + idx0], acc);
        }
        // scalar tail (empty when n % 4 == 0)
        for (int k = (n4 << 2) + idx0; k < n; k += gstride) {
            float t = targ[k];
            float d = pred[k] - t; float a = fmaf(d, d, PACK);
            int b = min(max((int)(t * 20.0f), 0), NBINS - 1);
            #pragma unroll
            for (int bb = 0; bb < NBINS; ++bb) acc[bb] += (bb == b) ? a : 0.0f;
        }
    }

    // ---- decode per thread (exact: cnt<=32, sse<32), stage sse in LDS ----
    #pragma unroll
    for (int b = 0; b < NBINS; ++b) {
        float A = acc[b];
        float c = floorf(A * (1.0f / 256.0f));
        float s = A - 256.0f * c;
        h[b * TPB + tid] = s;            // phase A payload
        acc[b] = c;                      // keep counts for phase B
    }
    __syncthreads();

    // ---- phase A: 160 readers, each sums 32 consecutive (staggered) slots ----
    const int rbin = tid >> 3;           // bin for readers (tid < 160)
    const int rchk = tid & 7;            // chunk within bin
    float pA = 0.0f;
    if (tid < NBINS * 8) {
        const int base = rbin * TPB + rchk * 32;
        #pragma unroll
        for (int k = 0; k < 32; ++k)
            pA += h[base + ((k + tid) & 31)];   // stagger -> conflict-free
    }
    pA += __shfl_down(pA, 4);            // combine 8 chunks (aligned groups)
    pA += __shfl_down(pA, 2);
    pA += __shfl_down(pA, 1);
    const float blk_sse = pA;            // valid at rchk==0

    __syncthreads();                     // phase A reads done -> reuse h
    #pragma unroll
    for (int b = 0; b < NBINS; ++b) h[b * TPB + tid] = acc[b];
    __syncthreads();

    float pB = 0.0f;
    if (tid < NBINS * 8) {
        const int base = rbin * TPB + rchk * 32;
        #pragma unroll
        for (int k = 0; k < 32; ++k)
            pB += h[base + ((k + tid) & 31)];
    }
    pB += __shfl_down(pB, 4);
    pB += __shfl_down(pB, 2);
    pB += __shfl_down(pB, 1);

    if (tid < NBINS * 8 && rchk == 0) {
        const int set = (int)(blockIdx.x) & setMask;
        unsafeAtomicAdd(&ws[set * 2 * NBINS + rbin], blk_sse);
        unsafeAtomicAdd(&ws[set * 2 * NBINS + NBINS + rbin], pB);
    }
}

// ---------------- Pass 2: weights + final scalar ----------------
__global__ void dwmse_pass2(const float* __restrict__ ws, float* __restrict__ out,
                            int nsets, float inv_n)
{
    const int t = threadIdx.x;   // 64 threads = 1 wave
    float col = 0.0f;
    if (t < 2 * NBINS) {
        for (int s = 0; s < nsets; ++s) col += ws[s * 2 * NBINS + t];
    }
    // lanes 0..19 hold sse_b; counts live in lanes 20..39
    float sse = col;
    float cnt = __shfl(col, t + 20);

    float w = 0.0f;
    if (t < NBINS) {
        float c = fmaxf(cnt, 1.0f);
        w = __powf(c, -0.9f);
    }
    float s = w;
    #pragma unroll
    for (int off = 32; off > 0; off >>= 1) s += __shfl_down(s, off);
    s = __shfl(s, 0);

    float wb = (s > 0.0f) ? (w * (20.0f / s)) : w;
    wb = fmaxf(wb, 1.0f);

    float contrib = (t < NBINS) ? (wb * sse) : 0.0f;
    #pragma unroll
    for (int off = 32; off > 0; off >>= 1) contrib += __shfl_down(contrib, off);

    if (t == 0) out[0] = contrib * inv_n;
}

extern "C" void kernel_launch(void* const* d_in, const int* in_sizes, int n_in,
                              void* d_out, int out_size, void* d_ws, size_t ws_size,
                              hipStream_t stream)
{
    const float* pred = (const float*)d_in[0];
    const float* targ = (const float*)d_in[1];
    float*       out  = (float*)d_out;
    float*       ws   = (float*)d_ws;
    const int n = in_sizes[0];

    int nsets = NSETS;
    while ((size_t)nsets * 2 * NBINS * sizeof(float) > ws_size && nsets > 1) nsets >>= 1;

    hipMemsetAsync(d_ws, 0, (size_t)nsets * 2 * NBINS * sizeof(float), stream);
    dwmse_pass1<<<BLOCKS, TPB, 0, stream>>>(pred, targ, ws, n, nsets - 1);
    dwmse_pass2<<<1, 64, 0, stream>>>(ws, out, nsets, 1.0f / (float)n);
}